// Round 5
// baseline (163.003 us; speedup 1.0000x reference)
//
#include <hip/hip_runtime.h>
#include <hip/hip_bf16.h>
#include <math.h>

// Shapes (fixed by the reference problem)
#define BB 2
#define TT 2048
#define CC 512
#define HH 8
#define DD 64
#define KK 4
#define C3 1536
#define MROWS (BB*TT)          // 4096

// GEMM tiling: 128x128, BK=32, 256 threads (4 waves, 2x2 quadrants of 64x64)
#define G1_NT (C3/128)                   // 12
#define G1_BLOCKS (G1_NT*(MROWS/128))    // 384
#define G2_NT (CC/128)                   // 4
#define G2_BLOCKS (G2_NT*(MROWS/128))    // 128

typedef __attribute__((ext_vector_type(8))) short bf16x8;
typedef __attribute__((ext_vector_type(4))) float floatx4;

static __device__ __forceinline__ unsigned short f2bf(float f) {
  unsigned int u = __float_as_uint(f);
  return (unsigned short)((u + 0x7fffu + ((u >> 16) & 1u)) >> 16);
}
static __device__ __forceinline__ float bf2f(unsigned short u) {
  return __uint_as_float(((unsigned int)u) << 16);
}

// ---------------------------------------------------------------------------
// GEMM body: C[M,N] = A[M,K] @ Bt[N,K]^T + bias. 128x128 tile, BK=32.
// (structure verified passing in round 2)
// ---------------------------------------------------------------------------
template<bool BF16OUT>
static __device__ __forceinline__ void gemm_body(
    int bid, int nt,
    const unsigned short* __restrict__ A,
    const unsigned short* __restrict__ Bt,
    const float* __restrict__ bias,
    void* __restrict__ Cout, int N, int K) {
  __shared__ bf16x8 As[128 * 4];   // [row][32 bf16]
  __shared__ bf16x8 Bs[128 * 4];
  const int tid  = threadIdx.x;
  const int wave = tid >> 6;
  const int lane = tid & 63;
  const int n0 = (bid % nt) * 128;
  const int m0 = (bid / nt) * 128;
  const int m_off = (wave >> 1) * 64;
  const int n_off = (wave & 1) * 64;
  const int lrow = lane >> 2;
  const int lcol = (lane & 3) * 8;
  const int fr = lane & 15;
  const int fq = lane >> 4;

  floatx4 acc[4][4];
#pragma unroll
  for (int i = 0; i < 4; ++i)
#pragma unroll
    for (int j = 0; j < 4; ++j) acc[i][j] = (floatx4){0.f, 0.f, 0.f, 0.f};

  for (int k0 = 0; k0 < K; k0 += 32) {
#pragma unroll
    for (int s = 0; s < 2; ++s) {
      int q = wave * 2 + s;          // 0..7 -> 128 rows
      const unsigned short* ga = A + (size_t)(m0 + q * 16 + lrow) * K + k0 + lcol;
      __builtin_amdgcn_global_load_lds(
          (const __attribute__((address_space(1))) void*)ga,
          (__attribute__((address_space(3))) void*)((char*)As + q * 1024), 16, 0, 0);
      const unsigned short* gb = Bt + (size_t)(n0 + q * 16 + lrow) * K + k0 + lcol;
      __builtin_amdgcn_global_load_lds(
          (const __attribute__((address_space(1))) void*)gb,
          (__attribute__((address_space(3))) void*)((char*)Bs + q * 1024), 16, 0, 0);
    }
    __syncthreads();
    bf16x8 a[4], b[4];
#pragma unroll
    for (int i = 0; i < 4; ++i) a[i] = As[(m_off + i * 16 + fr) * 4 + fq];
#pragma unroll
    for (int j = 0; j < 4; ++j) b[j] = Bs[(n_off + j * 16 + fr) * 4 + fq];
#pragma unroll
    for (int i = 0; i < 4; ++i)
#pragma unroll
      for (int j = 0; j < 4; ++j)
        acc[i][j] = __builtin_amdgcn_mfma_f32_16x16x32_bf16(a[i], b[j], acc[i][j], 0, 0, 0);
    __syncthreads();
  }
#pragma unroll
  for (int j = 0; j < 4; ++j) {
    int col = n0 + n_off + j * 16 + fr;
    float bv = bias[col];
#pragma unroll
    for (int i = 0; i < 4; ++i) {
#pragma unroll
      for (int r = 0; r < 4; ++r) {
        int row = m0 + m_off + i * 16 + fq * 4 + r;
        float v = acc[i][j][r] + bv;
        if (BF16OUT) ((unsigned short*)Cout)[(size_t)row * N + col] = f2bf(v);
        else {
          float* p = (float*)Cout + (size_t)row * N + col;
          __builtin_nontemporal_store(v, p);   // 'out' is never re-read
        }
      }
    }
  }
}

// ---------------------------------------------------------------------------
// top-4 body: exact, tie-break lower index (matches jax.lax.top_k)
// ---------------------------------------------------------------------------
static __device__ __forceinline__ void topk_body(
    int row, const float* __restrict__ tau, int* __restrict__ idx_out) {
  const int tid = threadIdx.x;
  const float4* rp = (const float4*)(tau + (size_t)row * TT);
  float v[8];
  float4 f0 = rp[tid * 2], f1 = rp[tid * 2 + 1];
  v[0]=f0.x; v[1]=f0.y; v[2]=f0.z; v[3]=f0.w;
  v[4]=f1.x; v[5]=f1.y; v[6]=f1.z; v[7]=f1.w;
  __shared__ float wv[4];
  __shared__ int wi[4];
  __shared__ int winner;
  const int base = tid * 8;
  int chosen[KK];
  for (int r = 0; r < KK; ++r) {
    float bv = v[0]; int bi = base;
#pragma unroll
    for (int i = 1; i < 8; ++i)
      if (v[i] > bv) { bv = v[i]; bi = base + i; }
#pragma unroll
    for (int off = 32; off > 0; off >>= 1) {
      float vv = __shfl_xor(bv, off, 64);
      int   ii = __shfl_xor(bi, off, 64);
      if (vv > bv || (vv == bv && ii < bi)) { bv = vv; bi = ii; }
    }
    if ((tid & 63) == 0) { wv[tid >> 6] = bv; wi[tid >> 6] = bi; }
    __syncthreads();
    if (tid == 0) {
      float b2 = wv[0]; int i2 = wi[0];
      for (int k = 1; k < 4; ++k)
        if (wv[k] > b2 || (wv[k] == b2 && wi[k] < i2)) { b2 = wv[k]; i2 = wi[k]; }
      winner = i2;
    }
    __syncthreads();
    int win = winner;
    chosen[r] = win;
    if ((win >> 3) == tid) v[win & 7] = -1e30f;
    __syncthreads();
  }
  if (tid < KK) idx_out[row * KK + tid] = chosen[tid];
}

// ---------------------------------------------------------------------------
// tau EMA + normalize + clip body (non-temporal output store)
// ---------------------------------------------------------------------------
static __device__ __forceinline__ void tau_body(
    int row, const float* __restrict__ tau, const int* __restrict__ idx_in,
    const float* __restrict__ sig_in, float* __restrict__ tau_out) {
  const int tid = threadIdx.x;
  int i4[KK]; float s3[KK];
#pragma unroll
  for (int j = 0; j < KK; ++j) {
    i4[j] = idx_in[row * KK + j];
    float s = sig_in[row * KK + j];
    s3[j] = s * s * s;
  }
  const float4* rp = (const float4*)(tau + (size_t)row * TT);
  float v[8];
  float4 f0 = rp[tid * 2], f1 = rp[tid * 2 + 1];
  v[0]=f0.x; v[1]=f0.y; v[2]=f0.z; v[3]=f0.w;
  v[4]=f1.x; v[5]=f1.y; v[6]=f1.z; v[7]=f1.w;
  const float keep = 1.0f - 0.085f;
  const int base = tid * 8;
  float local = 0.f;
#pragma unroll
  for (int i = 0; i < 8; ++i) {
    float t = keep * v[i];
#pragma unroll
    for (int j = 0; j < KK; ++j)
      if (base + i == i4[j]) t += s3[j];
    v[i] = t;
    local += t;
  }
#pragma unroll
  for (int off = 32; off > 0; off >>= 1) local += __shfl_xor(local, off, 64);
  __shared__ float wsum[4];
  __shared__ float tot;
  if ((tid & 63) == 0) wsum[tid >> 6] = local;
  __syncthreads();
  if (tid == 0) tot = wsum[0] + wsum[1] + wsum[2] + wsum[3];
  __syncthreads();
  float inv = 1.f / (tot + 1e-8f);
  floatx4* op = (floatx4*)(tau_out + (size_t)row * TT);
  floatx4 o0 = { fminf(v[0]*inv,5.f), fminf(v[1]*inv,5.f), fminf(v[2]*inv,5.f), fminf(v[3]*inv,5.f) };
  floatx4 o1 = { fminf(v[4]*inv,5.f), fminf(v[5]*inv,5.f), fminf(v[6]*inv,5.f), fminf(v[7]*inv,5.f) };
  __builtin_nontemporal_store(o0, op + tid * 2);
  __builtin_nontemporal_store(o1, op + tid * 2 + 1);
}

// ---------------------------------------------------------------------------
// transpose+convert body: W[R][Cn] fp32 -> Wt[Cn][R] bf16, 32x32 tiles
// ---------------------------------------------------------------------------
static __device__ __forceinline__ void transpose_body(
    int t, int nbx, const float* __restrict__ W, unsigned short* __restrict__ Wt,
    int R, int Cn) {
  __shared__ unsigned short tile[32][33];
  const int c0 = (t % nbx) * 32, r0 = (t / nbx) * 32;
  const int tx = threadIdx.x & 31, ty = threadIdx.x >> 5;
#pragma unroll
  for (int i = 0; i < 4; ++i) {
    int r = ty + i * 8;
    tile[r][tx] = f2bf(W[(size_t)(r0 + r) * Cn + c0 + tx]);
  }
  __syncthreads();
#pragma unroll
  for (int i = 0; i < 4; ++i) {
    int r = ty + i * 8;
    Wt[(size_t)(c0 + r) * R + r0 + tx] = tile[tx][r];
  }
}

// ---------------------------------------------------------------------------
// Kernel 1: all input conversions (x->bf16, Wqkv^T, Wproj^T)
// ---------------------------------------------------------------------------
__global__ __launch_bounds__(256) void prep_kernel(
    const float* __restrict__ x, unsigned short* __restrict__ x_bf,
    const float* __restrict__ Wqkv, unsigned short* __restrict__ wqkv_t,
    const float* __restrict__ Wproj, unsigned short* __restrict__ wproj_t) {
  const int bid = blockIdx.x;
  if (bid < 1024) {                       // convert x: 2M elements, 8/thread
    int g = bid * 256 + threadIdx.x;
    const float4* p = (const float4*)x;
    float4 f0 = p[g * 2], f1 = p[g * 2 + 1];
    union { unsigned short u[8]; uint4 v; } pk;
    pk.u[0]=f2bf(f0.x); pk.u[1]=f2bf(f0.y); pk.u[2]=f2bf(f0.z); pk.u[3]=f2bf(f0.w);
    pk.u[4]=f2bf(f1.x); pk.u[5]=f2bf(f1.y); pk.u[6]=f2bf(f1.z); pk.u[7]=f2bf(f1.w);
    ((uint4*)x_bf)[g] = pk.v;
  } else if (bid < 1024 + 768) {          // Wqkv [512,1536] -> [1536,512]
    transpose_body(bid - 1024, C3 / 32, Wqkv, wqkv_t, CC, C3);
  } else {                                // Wproj [512,512] -> [512,512]^T
    transpose_body(bid - 1792, CC / 32, Wproj, wproj_t, CC, CC);
  }
}

// ---------------------------------------------------------------------------
// Kernel 2: GEMM1 (qkv, bf16 out) blocks [0,384) + topk blocks [384,384+4096)
// ---------------------------------------------------------------------------
__global__ __launch_bounds__(256) void gemm1_topk_kernel(
    const unsigned short* __restrict__ x_bf,
    const unsigned short* __restrict__ wqkv_t,
    const float* __restrict__ bqkv, unsigned short* __restrict__ qkv_bf,
    const float* __restrict__ tau, int* __restrict__ idx_out) {
  if (blockIdx.x < G1_BLOCKS)
    gemm_body<true>(blockIdx.x, G1_NT, x_bf, wqkv_t, bqkv, qkv_bf, C3, CC);
  else
    topk_body(blockIdx.x - G1_BLOCKS, tau, idx_out);
}

// ---------------------------------------------------------------------------
// Kernel 3: sparse attention; all 8 gathered K/V loads issued up front,
// interleaved shuffle reductions (off-outer / j-inner).
// ---------------------------------------------------------------------------
__global__ __launch_bounds__(512) void attn_kernel(
    const unsigned short* __restrict__ qkv, const float* __restrict__ tau,
    const int* __restrict__ idx_in, unsigned short* __restrict__ attn_bf,
    float* __restrict__ sig_out) {
  const int row  = blockIdx.x;          // b*T + t
  const int b    = row >> 11;
  const int tid  = threadIdx.x;
  const int h    = tid >> 6;
  const int lane = tid & 63;

  __shared__ int   idx4[KK];
  __shared__ float tau4[KK];
  __shared__ float ps[HH][KK];
  if (tid < KK) {
    int s = idx_in[row * KK + tid];
    idx4[tid] = s;
    tau4[tid] = tau[(size_t)row * TT + s];
  }
  __syncthreads();

  const float q = bf2f(qkv[(size_t)row * C3 + h * DD + lane]);
  float kv[KK], vv[KK];
#pragma unroll
  for (int j = 0; j < KK; ++j) {
    size_t bs = ((size_t)(b * TT + idx4[j])) * C3 + h * DD + lane;
    kv[j] = bf2f(qkv[bs + CC]);
    vv[j] = bf2f(qkv[bs + 2 * CC]);
  }

  float p[KK];
#pragma unroll
  for (int j = 0; j < KK; ++j) p[j] = q * kv[j];
#pragma unroll
  for (int off = 32; off > 0; off >>= 1)
#pragma unroll
    for (int j = 0; j < KK; ++j) p[j] += __shfl_xor(p[j], off, 64);

  float logit[KK];
#pragma unroll
  for (int j = 0; j < KK; ++j)
    logit[j] = p[j] * 0.125f + 2.5f * logf(tau4[j] + 1e-8f);

  float m = fmaxf(fmaxf(logit[0], logit[1]), fmaxf(logit[2], logit[3]));
  float den = 0.f;
#pragma unroll
  for (int j = 0; j < KK; ++j) { p[j] = expf(logit[j] - m); den += p[j]; }
  float inv = 1.f / den;
#pragma unroll
  for (int j = 0; j < KK; ++j) p[j] *= inv;

  float o = 0.f;
#pragma unroll
  for (int j = 0; j < KK; ++j) o += p[j] * vv[j];
  attn_bf[(size_t)row * CC + h * DD + lane] = f2bf(o);

  if (lane < KK) ps[h][lane] = p[lane];
  __syncthreads();
  if (tid < KK) {
    float s = 0.f;
#pragma unroll
    for (int k = 0; k < HH; ++k) s += ps[k][tid];
    sig_out[row * KK + tid] = s * (1.0f / HH);
  }
}

// ---------------------------------------------------------------------------
// Kernel 4: GEMM2 (out, fp32) blocks [0,128) + tau update blocks [128,128+4096)
// ---------------------------------------------------------------------------
__global__ __launch_bounds__(256) void gemm2_tau_kernel(
    const unsigned short* __restrict__ attn_bf,
    const unsigned short* __restrict__ wproj_t,
    const float* __restrict__ bproj, float* __restrict__ out,
    const float* __restrict__ tau, const int* __restrict__ idx_in,
    const float* __restrict__ sig_in, float* __restrict__ tau_out) {
  if (blockIdx.x < G2_BLOCKS)
    gemm_body<false>(blockIdx.x, G2_NT, attn_bf, wproj_t, bproj, out, CC, CC);
  else
    tau_body(blockIdx.x - G2_BLOCKS, tau, idx_in, sig_in, tau_out);
}

// ---------------------------------------------------------------------------
extern "C" void kernel_launch(void* const* d_in, const int* in_sizes, int n_in,
                              void* d_out, int out_size, void* d_ws, size_t ws_size,
                              hipStream_t stream) {
  const float* x     = (const float*)d_in[0];   // [B,T,C]
  const float* tau   = (const float*)d_in[1];   // [B,T,T]
  const float* Wqkv  = (const float*)d_in[2];   // [C,3C]
  const float* bqkv  = (const float*)d_in[3];   // [3C]
  const float* Wproj = (const float*)d_in[4];   // [C,C]
  const float* bproj = (const float*)d_in[5];   // [C]

  float* out     = (float*)d_out;               // [B,T,C]
  float* tau_new = out + (size_t)MROWS * CC;    // [B,T,T]

  char* w = (char*)d_ws;
  unsigned short* qkv_bf  = (unsigned short*)w; w += (size_t)MROWS * C3 * 2;
  unsigned short* x_bf    = (unsigned short*)w; w += (size_t)MROWS * CC * 2;
  unsigned short* wqkv_t  = (unsigned short*)w; w += (size_t)C3 * CC * 2;
  unsigned short* wproj_t = (unsigned short*)w; w += (size_t)CC * CC * 2;
  unsigned short* attn_bf = (unsigned short*)w; w += (size_t)MROWS * CC * 2;
  int*   idx = (int*)w;                  w += (size_t)MROWS * KK * 4;
  float* sig = (float*)w;

  // 1) converts: x->bf16, Wqkv^T, Wproj^T
  prep_kernel<<<2048, 256, 0, stream>>>(x, x_bf, Wqkv, wqkv_t, Wproj, wproj_t);

  // 2) qkv GEMM (bf16 out, 128x128) + top-4 of tau rows, one kernel
  gemm1_topk_kernel<<<G1_BLOCKS + MROWS, 256, 0, stream>>>(
      x_bf, wqkv_t, bqkv, qkv_bf, tau, idx);

  // 3) sparse attention + signal
  attn_kernel<<<MROWS, 512, 0, stream>>>(qkv_bf, tau, idx, attn_bf, sig);

  // 4) out GEMM (fp32, 128x128) + tau update, one kernel
  gemm2_tau_kernel<<<G2_BLOCKS + MROWS, 256, 0, stream>>>(
      attn_bf, wproj_t, bproj, out, tau, idx, sig, tau_new);
}